// Round 3
// baseline (96.166 us; speedup 1.0000x reference)
//
#include <hip/hip_runtime.h>

// DAG reachability closure from node 0. N=8192 nodes, left/right child in
// [-1, N). Reference = N relaxation steps == transitive closure from node 0.
//
// SINGLE-WAVE barrier-free BFS in LDS:
//   - 256 threads stage edges (packed int2 -> one ds_read_b64/node) + write
//     output; wave 0 alone runs the fixpoint loop.
//   - Within one wave, DS ops complete in program order: an atomicOr issued
//     in iteration k is visible to every lane's re-read in iteration k+1.
//     => one BFS hop per iteration with ZERO barriers. Iterations = depth+1.
//   - Per-iteration critical path: 4 independent ds_read_b32 (own reach
//     words, ~130 cy) + __any. Sync cost ~ depth * 150 cy ~ 2-3 us total,
//     vs ~60K cycles of barrier+skew in the multi-wave versions.
//   - lane owns nodes [128L, 128L+128): private 'expanded' masks make total
//     expansion O(E); pending bits peeled 4-wide so 4 edge reads pipeline
//     per lgkmcnt wait; atomicOr fire-and-forget (off critical path).
// Output: bool mask -> INT32 0/1 (harness reads bool output as int32).

#define NMAX   8192
#define BLK    256
#define NWORDS (NMAX / 32)   // 256 reach words

__global__ __launch_bounds__(BLK) void dag_reach_kernel(
    const int* __restrict__ left,
    const int* __restrict__ right,
    int* __restrict__ out,
    int n)
{
    __shared__ int2 sLR[NMAX];               // 64 KB: packed (left, right)
    __shared__ unsigned int reach[NWORDS];   // 1 KB: reachable bitmask

    const int tid = threadIdx.x;

    // Stage edges: vectorized int4 global loads, packed int2 LDS writes.
    for (int i = 4 * tid; i < n; i += 4 * BLK) {
        int4 l4 = *reinterpret_cast<const int4*>(left  + i);
        int4 r4 = *reinterpret_cast<const int4*>(right + i);
        sLR[i + 0] = make_int2(l4.x, r4.x);
        sLR[i + 1] = make_int2(l4.y, r4.y);
        sLR[i + 2] = make_int2(l4.z, r4.z);
        sLR[i + 3] = make_int2(l4.w, r4.w);
    }
    for (int i = tid; i < NWORDS; i += BLK) reach[i] = (i == 0) ? 1u : 0u;
    __syncthreads();

    if (tid < 64) {                          // wave 0 only: barrier-free BFS
        const int lane  = tid;
        const int wbase = lane * 4;          // my 4 reach words
        const int nbase = lane * 128;        // my 128 nodes
        unsigned int exp0 = 0u, exp1 = 0u, exp2 = 0u, exp3 = 0u;
        volatile unsigned int* vreach = reach;

        while (true) {
            // 4 independent ds_read_b32 (one latency), then lockstep ballot.
            unsigned int p0 = vreach[wbase + 0] & ~exp0;
            unsigned int p1 = vreach[wbase + 1] & ~exp1;
            unsigned int p2 = vreach[wbase + 2] & ~exp2;
            unsigned int p3 = vreach[wbase + 3] & ~exp3;
            unsigned long long pa = ((unsigned long long)p1 << 32) | p0;
            unsigned long long pb = ((unsigned long long)p3 << 32) | p2;
            if (!__any((pa | pb) != 0ull)) break;   // fixpoint (wave-uniform)
            exp0 |= p0; exp1 |= p1; exp2 |= p2; exp3 |= p3;

            #pragma unroll
            for (int half = 0; half < 2; ++half) {
                unsigned long long p = half ? pb : pa;
                const int nb = nbase + (half << 6);
                while (p) {
                    // peel up to 4 pending bits -> 4 independent ds_read_b64
                    int b0 = __ffsll(p) - 1; p &= p - 1;
                    int b1 = -1, b2 = -1, b3 = -1;
                    if (p) { b1 = __ffsll(p) - 1; p &= p - 1;
                        if (p) { b2 = __ffsll(p) - 1; p &= p - 1;
                            if (p) { b3 = __ffsll(p) - 1; p &= p - 1; } } }
                    int2 e0 = sLR[nb + b0];
                    int2 e1 = sLR[nb + (b1 < 0 ? b0 : b1)];
                    int2 e2 = sLR[nb + (b2 < 0 ? b0 : b2)];
                    int2 e3 = sLR[nb + (b3 < 0 ? b0 : b3)];
                    if (e0.x >= 0) atomicOr(&reach[e0.x >> 5], 1u << (e0.x & 31));
                    if (e0.y >= 0) atomicOr(&reach[e0.y >> 5], 1u << (e0.y & 31));
                    if (b1 >= 0) {
                        if (e1.x >= 0) atomicOr(&reach[e1.x >> 5], 1u << (e1.x & 31));
                        if (e1.y >= 0) atomicOr(&reach[e1.y >> 5], 1u << (e1.y & 31));
                    }
                    if (b2 >= 0) {
                        if (e2.x >= 0) atomicOr(&reach[e2.x >> 5], 1u << (e2.x & 31));
                        if (e2.y >= 0) atomicOr(&reach[e2.y >> 5], 1u << (e2.y & 31));
                    }
                    if (b3 >= 0) {
                        if (e3.x >= 0) atomicOr(&reach[e3.x >> 5], 1u << (e3.x & 31));
                        if (e3.y >= 0) atomicOr(&reach[e3.y >> 5], 1u << (e3.y & 31));
                    }
                }
            }
            __threadfence_block();   // drain atomics before next re-read
        }
    }
    __syncthreads();                 // waves 1-3 parked here during BFS

    // Write bool mask as int32 0/1, vectorized (16 B per lane, coalesced).
    for (int i = 4 * tid; i < n; i += 4 * BLK) {
        const unsigned w = reach[i >> 5];
        const int b = i & 31;
        *reinterpret_cast<int4*>(out + i) =
            make_int4((int)((w >> (b + 0)) & 1u),
                      (int)((w >> (b + 1)) & 1u),
                      (int)((w >> (b + 2)) & 1u),
                      (int)((w >> (b + 3)) & 1u));
    }
}

extern "C" void kernel_launch(void* const* d_in, const int* in_sizes, int n_in,
                              void* d_out, int out_size, void* d_ws, size_t ws_size,
                              hipStream_t stream)
{
    // inputs: 0 = thresholds (f32, UNUSED by reference), 1 = left (i32), 2 = right (i32)
    const int* left  = (const int*)d_in[1];
    const int* right = (const int*)d_in[2];
    int* out = (int*)d_out;
    const int n = in_sizes[1];

    dag_reach_kernel<<<1, BLK, 0, stream>>>(left, right, out, n);
}

// Round 4
// 74.327 us; speedup vs baseline: 1.2938x; 1.2938x over previous
//
#include <hip/hip_runtime.h>

// DAG reachability closure from node 0. N=8192 nodes, left/right child in
// [-1, N). Reference = N relaxation steps == transitive closure from node 0.
//
// Chaotic bitmask relaxation in LDS — R0's winning shape (1024 threads =
// 16 waves, thread t owns nodes [8t,8t+8)), with the barrier tax removed:
//   - ONE barrier per pass (was 2) via a mod-3 rotating flag: pass p sets
//     flag[p%3] on change, resets flag[(p+1)%3], barriers, reads flag[p%3].
//     Max skew = 1 pass, and in that window no thread writes slot p%3, so
//     the break decision is uniform (no divergent-break deadlock).
//   - INNER=4 barrier-free sub-iterations per pass: LDS atomics are visible
//     as soon as they complete, and 16 waves interleave on 4 SIMDs, so each
//     pass propagates multiple BFS hops -> ~10 passes instead of ~35.
//     Termination exact: a pass where nobody saw pending bits means no
//     atomics were issued that pass -> state was already the fixpoint.
//   - edges packed int2 in LDS: one ds_read_b64 per expanded node; pending
//     bits peeled 4-wide so 4 edge reads share one lgkmcnt wait.
//   - atomicOr fire-and-forget (result unused -> off the critical path);
//     flag set is wave-aggregated (__any + lane 0), one store per wave.
// Output: bool mask -> INT32 0/1 (harness reads bool output as int32).

#define NMAX   8192
#define BLK    1024
#define NWORDS (NMAX / 32)
#define INNER  4

__global__ __launch_bounds__(BLK) void dag_reach_kernel(
    const int* __restrict__ left,
    const int* __restrict__ right,
    int* __restrict__ out,
    int n)
{
    __shared__ int2 sLR[NMAX];               // 64 KB: packed (left, right)
    __shared__ unsigned int reach[NWORDS];   // 1 KB: reachable bitmask
    __shared__ int s_flag[3];                // rotating change flags

    const int tid = threadIdx.x;

    // Stage edges: 8 nodes/thread, int4 global loads, packed int2 LDS writes.
    {
        const int i = 8 * tid;
        if (i + 7 < n) {
            int4 l0 = *reinterpret_cast<const int4*>(left  + i);
            int4 l1 = *reinterpret_cast<const int4*>(left  + i + 4);
            int4 r0 = *reinterpret_cast<const int4*>(right + i);
            int4 r1 = *reinterpret_cast<const int4*>(right + i + 4);
            sLR[i + 0] = make_int2(l0.x, r0.x);
            sLR[i + 1] = make_int2(l0.y, r0.y);
            sLR[i + 2] = make_int2(l0.z, r0.z);
            sLR[i + 3] = make_int2(l0.w, r0.w);
            sLR[i + 4] = make_int2(l1.x, r1.x);
            sLR[i + 5] = make_int2(l1.y, r1.y);
            sLR[i + 6] = make_int2(l1.z, r1.z);
            sLR[i + 7] = make_int2(l1.w, r1.w);
        } else {
            for (int k = i; k < n; ++k) sLR[k] = make_int2(left[k], right[k]);
        }
    }
    if (tid < NWORDS) reach[tid] = (tid == 0) ? 1u : 0u;
    if (tid < 3)      s_flag[tid] = 0;
    __syncthreads();

    const int word_idx = tid >> 2;           // my reach word
    const int shift    = (tid & 3) * 8;      // my byte within it
    const int base     = tid * 8;            // my 8 nodes
    unsigned int expanded = 0u;              // bits already pushed (8 used)
    volatile unsigned int* vreach = reach;

    int p3 = 0;                              // pass index mod 3
    while (true) {
        const int pn3 = (p3 == 2) ? 0 : p3 + 1;
        int ch = 0;

        #pragma unroll
        for (int it = 0; it < INNER; ++it) {
            unsigned int pend = ((vreach[word_idx] >> shift) & 0xFFu) & ~expanded;
            if (pend) {
                ch = 1;
                expanded |= pend;
                while (pend) {
                    // peel up to 4 pending bits -> 4 independent ds_read_b64
                    int b0 = __ffs(pend) - 1; pend &= pend - 1;
                    int b1 = -1, b2 = -1, b3 = -1;
                    if (pend) { b1 = __ffs(pend) - 1; pend &= pend - 1;
                        if (pend) { b2 = __ffs(pend) - 1; pend &= pend - 1;
                            if (pend) { b3 = __ffs(pend) - 1; pend &= pend - 1; } } }
                    int2 e0 = sLR[base + b0];
                    int2 e1 = sLR[base + (b1 < 0 ? b0 : b1)];
                    int2 e2 = sLR[base + (b2 < 0 ? b0 : b2)];
                    int2 e3 = sLR[base + (b3 < 0 ? b0 : b3)];
                    if (e0.x >= 0) atomicOr(&reach[e0.x >> 5], 1u << (e0.x & 31));
                    if (e0.y >= 0) atomicOr(&reach[e0.y >> 5], 1u << (e0.y & 31));
                    if (b1 >= 0) {
                        if (e1.x >= 0) atomicOr(&reach[e1.x >> 5], 1u << (e1.x & 31));
                        if (e1.y >= 0) atomicOr(&reach[e1.y >> 5], 1u << (e1.y & 31));
                    }
                    if (b2 >= 0) {
                        if (e2.x >= 0) atomicOr(&reach[e2.x >> 5], 1u << (e2.x & 31));
                        if (e2.y >= 0) atomicOr(&reach[e2.y >> 5], 1u << (e2.y & 31));
                    }
                    if (b3 >= 0) {
                        if (e3.x >= 0) atomicOr(&reach[e3.x >> 5], 1u << (e3.x & 31));
                        if (e3.y >= 0) atomicOr(&reach[e3.y >> 5], 1u << (e3.y & 31));
                    }
                }
            }
        }

        // Wave-aggregated flag update + next-slot reset (benign same-value races).
        if ((tid & 63) == 0) s_flag[pn3] = 0;
        if (__any(ch) && (tid & 63) == 0) s_flag[p3] = 1;
        __syncthreads();                     // the ONLY barrier per pass
        if (!s_flag[p3]) break;              // uniform: fixpoint reached
        p3 = pn3;
    }

    // Write bool mask as int32 0/1, vectorized (16 B per lane, coalesced).
    for (int i = 4 * tid; i < n; i += 4 * BLK) {
        const unsigned w = reach[i >> 5];
        const int b = i & 31;
        *reinterpret_cast<int4*>(out + i) =
            make_int4((int)((w >> (b + 0)) & 1u),
                      (int)((w >> (b + 1)) & 1u),
                      (int)((w >> (b + 2)) & 1u),
                      (int)((w >> (b + 3)) & 1u));
    }
}

extern "C" void kernel_launch(void* const* d_in, const int* in_sizes, int n_in,
                              void* d_out, int out_size, void* d_ws, size_t ws_size,
                              hipStream_t stream)
{
    // inputs: 0 = thresholds (f32, UNUSED by reference), 1 = left (i32), 2 = right (i32)
    const int* left  = (const int*)d_in[1];
    const int* right = (const int*)d_in[2];
    int* out = (int*)d_out;
    const int n = in_sizes[1];

    dag_reach_kernel<<<1, BLK, 0, stream>>>(left, right, out, n);
}